// Round 9
// baseline (400.760 us; speedup 1.0000x reference)
//
#include <hip/hip_runtime.h>
#include <stdint.h>
#include <math.h>

using f32x4  = __attribute__((ext_vector_type(4)))  float;
using f32x16 = __attribute__((ext_vector_type(16))) float;
using s16x8  = __attribute__((ext_vector_type(8)))  short;

#define DI __device__ __forceinline__

DI unsigned short f2bf(float f) {
  unsigned u = __float_as_uint(f);
  u += 0x7FFFu + ((u >> 16) & 1u);
  return (unsigned short)(u >> 16);
}
DI float bf2f(unsigned short h) { return __uint_as_float((unsigned)h << 16); }

// ---------------------------------------------------------------- f32 -> bf16
__global__ void k_cvt_bf16(const float* __restrict__ in, unsigned short* __restrict__ out, int n4) {
  int i = blockIdx.x * blockDim.x + threadIdx.x;
  const int stride = gridDim.x * blockDim.x;
  for (; i < n4; i += stride) {
    float4 v = reinterpret_cast<const float4*>(in)[i];
    ushort4 o;
    o.x = f2bf(v.x); o.y = f2bf(v.y); o.z = f2bf(v.z); o.w = f2bf(v.w);
    reinterpret_cast<ushort4*>(out)[i] = o;
  }
}

// ---------------------------------------------------------------- rope tables (2048 x 32)
__global__ void k_rope_table(float* __restrict__ cost, float* __restrict__ sint) {
  const int idx = blockIdx.x * 256 + threadIdx.x;  // 65536
  const int s = idx >> 5, fi = idx & 31;
  const double invf = pow(10000.0, -(double)fi / 32.0);
  const float ang = (float)s * (float)invf;
  cost[idx] = (float)cos((double)ang);
  sint[idx] = (float)sin((double)ang);
}

// ---------------------------------------------------------------- bf16 GEMM  C[M][N] = A[M][K]*B[N][K]^T + bias
__global__ __launch_bounds__(256) void k_gemm_bt(
    const unsigned short* __restrict__ A, const unsigned short* __restrict__ B,
    const float* __restrict__ bias, float* __restrict__ C, int M, int N, int K) {
  __shared__ unsigned short As[128 * 32], Bs[128 * 32];
  const int tid = threadIdx.x, l = tid & 63, w = tid >> 6;
  const int wr = w >> 1, wc = w & 1;
  const int m0 = blockIdx.x * 128, n0 = blockIdx.y * 128;
  const int srow = tid >> 2, scol = (tid & 3) * 8;
  f32x4 acc[4][4] = {};
  for (int k0 = 0; k0 < K; k0 += 32) {
    s16x8 a0 = *(const s16x8*)(A + (size_t)(m0 + srow) * K + k0 + scol);
    s16x8 a1 = *(const s16x8*)(A + (size_t)(m0 + 64 + srow) * K + k0 + scol);
    s16x8 b0 = *(const s16x8*)(B + (size_t)(n0 + srow) * K + k0 + scol);
    s16x8 b1 = *(const s16x8*)(B + (size_t)(n0 + 64 + srow) * K + k0 + scol);
    __syncthreads();
    *(s16x8*)&As[srow * 32 + scol] = a0;
    *(s16x8*)&As[(64 + srow) * 32 + scol] = a1;
    *(s16x8*)&Bs[srow * 32 + scol] = b0;
    *(s16x8*)&Bs[(64 + srow) * 32 + scol] = b1;
    __syncthreads();
    s16x8 af[4], bf[4];
#pragma unroll
    for (int i = 0; i < 4; i++)
      af[i] = *(const s16x8*)&As[(wr * 64 + i * 16 + (l & 15)) * 32 + (l >> 4) * 8];
#pragma unroll
    for (int j = 0; j < 4; j++)
      bf[j] = *(const s16x8*)&Bs[(wc * 64 + j * 16 + (l & 15)) * 32 + (l >> 4) * 8];
#pragma unroll
    for (int i = 0; i < 4; i++)
#pragma unroll
      for (int j = 0; j < 4; j++)
        acc[i][j] = __builtin_amdgcn_mfma_f32_16x16x32_bf16(af[i], bf[j], acc[i][j], 0, 0, 0);
  }
#pragma unroll
  for (int i = 0; i < 4; i++) {
    const int row = m0 + wr * 64 + i * 16 + (l >> 4) * 4;
#pragma unroll
    for (int j = 0; j < 4; j++) {
      const int col = n0 + wc * 64 + j * 16 + (l & 15);
      const float bv = bias ? bias[col] : 0.f;
#pragma unroll
      for (int r = 0; r < 4; r++) C[(size_t)(row + r) * N + col] = acc[i][j][r] + bv;
    }
  }
}

// ---------------------------------------------------------------- RoPE + relayout
// rotate_half pairs heads h^8 (sign - for h<8); tables indexed by (s, d&31).
__global__ void k_rope_relayout(const float* __restrict__ qkv, const float* __restrict__ cost,
                                const float* __restrict__ sint,
                                unsigned short* __restrict__ qh, unsigned short* __restrict__ kh,
                                unsigned short* __restrict__ vt) {
  const int s = blockIdx.x, t = threadIdx.x;
  const float* row = qkv + (size_t)s * 3072;
  const int c = t * 4;
  const int d = c >> 4;
  const int hbase = c & 15;
  const float cv = cost[s * 32 + (d & 31)];
  const float sv = sint[s * 32 + (d & 31)];
  const float sgn = (hbase < 8) ? -1.f : 1.f;
  {
    float4 v = *(const float4*)(row + c);
    float4 v2 = *(const float4*)(row + (c ^ 8));
    const float* vp = (const float*)&v;
    const float* vp2 = (const float*)&v2;
#pragma unroll
    for (int i = 0; i < 4; i++) {
      float val = vp[i] * cv + sgn * vp2[i] * sv;
      qh[(size_t)(hbase + i) * (2048 * 64) + s * 64 + d] = f2bf(val);
    }
  }
  {
    float4 v = *(const float4*)(row + 1024 + c);
    float4 v2 = *(const float4*)(row + 1024 + (c ^ 8));
    const float* vp = (const float*)&v;
    const float* vp2 = (const float*)&v2;
#pragma unroll
    for (int i = 0; i < 4; i++) {
      float val = vp[i] * cv + sgn * vp2[i] * sv;
      kh[(size_t)(hbase + i) * (2048 * 64) + s * 64 + d] = f2bf(val);
    }
  }
  {
    float4 v = *(const float4*)(row + 2048 + c);
    const float* vp = (const float*)&v;
#pragma unroll
    for (int i = 0; i < 4; i++)
      vt[(size_t)(hbase + i) * (64 * 2048) + (size_t)d * 2048 + s] = f2bf(vp[i]);
  }
}

// ---------------------------------------------------------------- fused mask+cast (PURE LINEAR stream, 2x wide)
// bm16[j][k][h] = bf16(mask ? bias : -1e8)   -- same linear index as inputs.
__global__ void k_mask(const float* __restrict__ bias, const int* __restrict__ mask,
                       unsigned short* __restrict__ bm16, int n16) {
  int i = blockIdx.x * blockDim.x + threadIdx.x;
  const int stride = gridDim.x * blockDim.x;
  for (; i < n16; i += stride) {
    float4 b0 = reinterpret_cast<const float4*>(bias)[4 * i];
    float4 b1 = reinterpret_cast<const float4*>(bias)[4 * i + 1];
    float4 b2 = reinterpret_cast<const float4*>(bias)[4 * i + 2];
    float4 b3 = reinterpret_cast<const float4*>(bias)[4 * i + 3];
    int4 m0 = reinterpret_cast<const int4*>(mask)[4 * i];
    int4 m1 = reinterpret_cast<const int4*>(mask)[4 * i + 1];
    int4 m2 = reinterpret_cast<const int4*>(mask)[4 * i + 2];
    int4 m3 = reinterpret_cast<const int4*>(mask)[4 * i + 3];
    uint4 o0, o1;
    o0.x = (unsigned)f2bf(m0.x ? b0.x : -1.0e8f) | ((unsigned)f2bf(m0.y ? b0.y : -1.0e8f) << 16);
    o0.y = (unsigned)f2bf(m0.z ? b0.z : -1.0e8f) | ((unsigned)f2bf(m0.w ? b0.w : -1.0e8f) << 16);
    o0.z = (unsigned)f2bf(m1.x ? b1.x : -1.0e8f) | ((unsigned)f2bf(m1.y ? b1.y : -1.0e8f) << 16);
    o0.w = (unsigned)f2bf(m1.z ? b1.z : -1.0e8f) | ((unsigned)f2bf(m1.w ? b1.w : -1.0e8f) << 16);
    o1.x = (unsigned)f2bf(m2.x ? b2.x : -1.0e8f) | ((unsigned)f2bf(m2.y ? b2.y : -1.0e8f) << 16);
    o1.y = (unsigned)f2bf(m2.z ? b2.z : -1.0e8f) | ((unsigned)f2bf(m2.w ? b2.w : -1.0e8f) << 16);
    o1.z = (unsigned)f2bf(m3.x ? b3.x : -1.0e8f) | ((unsigned)f2bf(m3.y ? b3.y : -1.0e8f) << 16);
    o1.w = (unsigned)f2bf(m3.z ? b3.z : -1.0e8f) | ((unsigned)f2bf(m3.w ? b3.w : -1.0e8f) << 16);
    reinterpret_cast<uint4*>(bm16)[2 * i] = o0;
    reinterpret_cast<uint4*>(bm16)[2 * i + 1] = o1;
  }
}

// ---------------------------------------------------------------- attention v3
// 8 waves (h8 per block), grid (hg=2, jt=64, ks=4) = 512 blocks = 2/CU.
// Per k32 iter: stage j32 x k32 x h8 bf16 tile (16 KB) via global_load_lds
// (2 instrs/wave), 3-buffer ring, counted vmcnt(2) + one s_barrier per iter.
// Source k-slot XOR-preswizzle (slot = k ^ (j&7)) -> <=4-way LDS conflicts.
#define GLDS16(gp, lp)                                                            \
  __builtin_amdgcn_global_load_lds(                                               \
      (const __attribute__((address_space(1))) unsigned int*)(const void*)(gp),   \
      (__attribute__((address_space(3))) unsigned int*)(void*)(lp), 16, 0, 0)

__global__ __launch_bounds__(512, 4) void k_attn(
    const unsigned short* __restrict__ bm16,
    const unsigned short* __restrict__ qh, const unsigned short* __restrict__ kh,
    const unsigned short* __restrict__ vt,
    float* __restrict__ Opart, float* __restrict__ ML) {
  __shared__ unsigned short tile[3][32][32][8];  // 48 KB ring: [buf][j][kslot][h8]
  const int tid = threadIdx.x, l = tid & 63, w = tid >> 6;  // w = head-in-group
  const int hi = l >> 5, ln = l & 31;
  const int hg = blockIdx.x, jt = blockIdx.y, ks = blockIdx.z;
  const int j0 = jt * 32, kstart = ks * 512, h = hg * 8 + w;

  s16x8 qf[4];
  {
    const unsigned short* qb = qh + ((size_t)h * 2048 + (j0 + ln)) * 64 + 8 * hi;
#pragma unroll
    for (int ds = 0; ds < 4; ds++) qf[ds] = *(const s16x8*)(qb + ds * 16);
  }
  const unsigned short* kb = kh + ((size_t)h * 2048 + (kstart + ln)) * 64 + 8 * hi;
  const unsigned short* vb = vt + (size_t)h * 64 * 2048 + (size_t)ln * 2048 + kstart + 8 * hi;

  // stage: wave w covers rows 4w + 2*i + (l>>5); lane slot ln holds logical
  // k = ln ^ (jrow & 7)  (involution). src u16 index:
  const int jr0 = 4 * w + hi;       // instr 0 rows (hi=lane>=32 -> +1)
  const int jr1 = jr0 + 2;          // instr 1 rows
  const unsigned short* src0 = bm16 + ((size_t)(j0 + jr0) * 2048 + kstart + (ln ^ (jr0 & 7))) * 16 + hg * 8;
  const unsigned short* src1 = bm16 + ((size_t)(j0 + jr1) * 2048 + kstart + (ln ^ (jr1 & 7))) * 16 + hg * 8;

#define STAGE(m)                                            \
  {                                                         \
    const int bi_ = (m) % 3;                                \
    GLDS16(src0 + (size_t)(m) * 512, &tile[bi_][4 * w][0][0]);      \
    GLDS16(src1 + (size_t)(m) * 512, &tile[bi_][4 * w + 2][0][0]);  \
  }

  f32x16 o0 = {}, o1 = {};
  float mrun = -3.0e38f, lrun = 0.f;

  STAGE(0)

  for (int m = 0; m < 16; ++m) {
    // K/V loads for THIS iter first (so the 2 newest outstanding = stage loads)
    s16x8 kf[4], vf[4];
    {
      const unsigned short* kp = kb + (size_t)m * (32 * 64);
#pragma unroll
      for (int ds = 0; ds < 4; ds++) kf[ds] = *(const s16x8*)(kp + ds * 16);
      const unsigned short* vp = vb + (size_t)m * 32;
      vf[0] = *(const s16x8*)(vp);
      vf[1] = *(const s16x8*)(vp + 32 * 2048);
      vf[2] = *(const s16x8*)(vp + 16);
      vf[3] = *(const s16x8*)(vp + 32 * 2048 + 16);
    }
    if (m + 1 < 16) {
      STAGE(m + 1)
      asm volatile("s_waitcnt vmcnt(2)\n\ts_barrier" ::: "memory");
    } else {
      asm volatile("s_waitcnt vmcnt(0)\n\ts_barrier" ::: "memory");
    }
    const int bi = m % 3;
    // S^T = K*Q^T : reg r -> kl=(r&3)+8*(r>>2)+4*hi, lane ln -> j
    f32x16 st = {};
#pragma unroll
    for (int ds = 0; ds < 4; ds++)
      st = __builtin_amdgcn_mfma_f32_32x32x16_bf16(kf[ds], qf[ds], st, 0, 0, 0);
    float p[16];
    float tmax = -3.0e38f;
#pragma unroll
    for (int r = 0; r < 16; r++) {
      const int kl = (r & 3) + 8 * (r >> 2) + 4 * hi;
      const unsigned short u = tile[bi][ln][kl ^ (ln & 7)][w];
      const float sv = st[r] * 0.125f + bf2f(u);
      p[r] = sv;
      tmax = fmaxf(tmax, sv);
    }
    tmax = fmaxf(tmax, __shfl_xor(tmax, 32));
    const float mnew = fmaxf(mrun, tmax);
    const float sc = __expf(mrun - mnew);
    float psum = 0.f;
#pragma unroll
    for (int r = 0; r < 16; r++) { p[r] = __expf(p[r] - mnew); psum += p[r]; }
    psum += __shfl_xor(psum, 32);
    lrun = lrun * sc + psum;
    mrun = mnew;
#pragma unroll
    for (int r = 0; r < 16; r++) {
      const int jj = (r & 3) + 8 * (r >> 2) + 4 * hi;
      const float s2 = __shfl(sc, jj);
      o0[r] *= s2;
      o1[r] *= s2;
    }
    unsigned pk[8];
#pragma unroll
    for (int q = 0; q < 8; q++)
      pk[q] = (unsigned)f2bf(p[2 * q]) | ((unsigned)f2bf(p[2 * q + 1]) << 16);
#pragma unroll
    for (int s = 0; s < 2; s++) {
      const unsigned a0 = pk[4 * s + 0], a1 = pk[4 * s + 1];
      const unsigned a2 = pk[4 * s + 2], a3 = pk[4 * s + 3];
      const unsigned x0 = (unsigned)__shfl_xor((int)a0, 32);
      const unsigned x1 = (unsigned)__shfl_xor((int)a1, 32);
      const unsigned x2 = (unsigned)__shfl_xor((int)a2, 32);
      const unsigned x3 = (unsigned)__shfl_xor((int)a3, 32);
      union { int4 i; s16x8 v; } u;
      u.i.x = (int)(hi ? x2 : a0);
      u.i.y = (int)(hi ? x3 : a1);
      u.i.z = (int)(hi ? a2 : x0);
      u.i.w = (int)(hi ? a3 : x1);
      o0 = __builtin_amdgcn_mfma_f32_32x32x16_bf16(u.v, vf[2 * s + 0], o0, 0, 0, 0);
      o1 = __builtin_amdgcn_mfma_f32_32x32x16_bf16(u.v, vf[2 * s + 1], o1, 0, 0, 0);
    }
  }
#undef STAGE

  // Opart layout [ks][jt][h][j32][d64], ML [ks][jt][h][j32][2]
  float* ob = Opart + (((size_t)(ks * 64 + jt) * 16 + h) * 32) * 64;
#pragma unroll
  for (int r = 0; r < 16; r++) {
    const int jj = (r & 3) + 8 * (r >> 2) + 4 * hi;
    ob[(size_t)jj * 64 + ln] = o0[r];
    ob[(size_t)jj * 64 + 32 + ln] = o1[r];
  }
  if (hi == 0) {
    float* mlp = ML + (((size_t)(ks * 64 + jt) * 16 + h) * 32 + ln) * 2;
    mlp[0] = mrun;
    mlp[1] = lrun;
  }
}

// ---------------------------------------------------------------- combine k-splits -> attn_flat bf16 [2048][1024]
__global__ void k_combine(const float* __restrict__ Opart, const float* __restrict__ ML,
                          unsigned short* __restrict__ attn_flat) {
  const int j = blockIdx.x, t = threadIdx.x;
  const int jt = j >> 5, jl = j & 31;
  const int d = t >> 2;
  unsigned short tmp[4];
#pragma unroll
  for (int q = 0; q < 4; q++) {
    const int hh = 4 * (t & 3) + q;
    float m[4], lv[4];
#pragma unroll
    for (int ksi = 0; ksi < 4; ksi++) {
      const size_t base = ((size_t)(ksi * 64 + jt) * 16 + hh) * 32 + jl;
      m[ksi] = ML[base * 2];
      lv[ksi] = ML[base * 2 + 1];
    }
    const float M = fmaxf(fmaxf(m[0], m[1]), fmaxf(m[2], m[3]));
    float L = 0.f, acc = 0.f;
#pragma unroll
    for (int ksi = 0; ksi < 4; ksi++) {
      const float e = __expf(m[ksi] - M);
      L += lv[ksi] * e;
      const size_t base = ((size_t)(ksi * 64 + jt) * 16 + hh) * 32 + jl;
      acc += Opart[base * 64 + d] * e;
    }
    tmp[q] = f2bf(acc / L);
  }
  ushort4 outv;
  outv.x = tmp[0]; outv.y = tmp[1]; outv.z = tmp[2]; outv.w = tmp[3];
  *(ushort4*)(attn_flat + (size_t)j * 1024 + t * 4) = outv;
}

// ---------------------------------------------------------------- launch
extern "C" void kernel_launch(void* const* d_in, const int* in_sizes, int n_in,
                              void* d_out, int out_size, void* d_ws, size_t ws_size,
                              hipStream_t stream) {
  const float* x     = (const float*)d_in[0];
  const float* bias  = (const float*)d_in[1];
  const int*   mask  = (const int*)d_in[2];
  const float* w_qkv = (const float*)d_in[3];
  const float* b_qkv = (const float*)d_in[4];
  const float* w_out = (const float*)d_in[5];
  const float* b_out = (const float*)d_in[6];
  float* out = (float*)d_out;

  char* ws = (char*)d_ws;
  unsigned short* xb   = (unsigned short*)(ws);                      // 4 MB
  unsigned short* wqb  = (unsigned short*)(ws + ((size_t)4 << 20));  // 6 MB
  unsigned short* wob  = (unsigned short*)(ws + ((size_t)10 << 20)); // 2 MB
  float* cost          = (float*)(ws + ((size_t)12 << 20));
  float* sint          = (float*)(ws + ((size_t)12 << 20) + (256 << 10));
  float* qkv           = (float*)(ws + ((size_t)13 << 20));          // 24 MB
  unsigned short* qhp  = (unsigned short*)(ws + ((size_t)37 << 20)); // 4 MB
  unsigned short* khp  = (unsigned short*)(ws + ((size_t)41 << 20)); // 4 MB
  unsigned short* vtp  = (unsigned short*)(ws + ((size_t)45 << 20)); // 4 MB
  unsigned short* af   = (unsigned short*)(ws + ((size_t)49 << 20)); // 4 MB
  float* Opart         = (float*)(ws + ((size_t)53 << 20));          // 33.6 MB
  float* ML            = (float*)(ws + ((size_t)88 << 20));          // 1 MB
  unsigned short* bm16 = (unsigned short*)(ws + ((size_t)90 << 20)); // 128 MB

  k_cvt_bf16<<<dim3(512), dim3(256), 0, stream>>>(x, xb, 2048 * 1024 / 4);
  k_cvt_bf16<<<dim3(512), dim3(256), 0, stream>>>(w_qkv, wqb, 3072 * 1024 / 4);
  k_cvt_bf16<<<dim3(512), dim3(256), 0, stream>>>(w_out, wob, 1024 * 1024 / 4);
  k_rope_table<<<dim3(256), dim3(256), 0, stream>>>(cost, sint);
  k_mask<<<dim3(2048), dim3(256), 0, stream>>>(bias, mask, bm16, 2048 * 2048 * 16 / 16);
  k_gemm_bt<<<dim3(16, 24), dim3(256), 0, stream>>>(xb, wqb, b_qkv, qkv, 2048, 3072, 1024);
  k_rope_relayout<<<dim3(2048), dim3(256), 0, stream>>>(qkv, cost, sint, qhp, khp, vtp);
  k_attn<<<dim3(2, 64, 4), dim3(512), 0, stream>>>(bm16, qhp, khp, vtp, Opart, ML);
  k_combine<<<dim3(2048), dim3(256), 0, stream>>>(Opart, ML, af);
  k_gemm_bt<<<dim3(16, 8), dim3(256), 0, stream>>>(af, wob, b_out, out, 2048, 1024, 1024);
}

// Round 10
// 322.070 us; speedup vs baseline: 1.2443x; 1.2443x over previous
//
#include <hip/hip_runtime.h>
#include <stdint.h>
#include <math.h>

using f32x4  = __attribute__((ext_vector_type(4)))  float;
using f32x16 = __attribute__((ext_vector_type(16))) float;
using s16x8  = __attribute__((ext_vector_type(8)))  short;

#define DI __device__ __forceinline__

DI unsigned short f2bf(float f) {
  unsigned u = __float_as_uint(f);
  u += 0x7FFFu + ((u >> 16) & 1u);
  return (unsigned short)(u >> 16);
}
DI float bf2f(unsigned short h) { return __uint_as_float((unsigned)h << 16); }

// ---------------------------------------------------------------- f32 -> bf16
__global__ void k_cvt_bf16(const float* __restrict__ in, unsigned short* __restrict__ out, int n4) {
  int i = blockIdx.x * blockDim.x + threadIdx.x;
  const int stride = gridDim.x * blockDim.x;
  for (; i < n4; i += stride) {
    float4 v = reinterpret_cast<const float4*>(in)[i];
    ushort4 o;
    o.x = f2bf(v.x); o.y = f2bf(v.y); o.z = f2bf(v.z); o.w = f2bf(v.w);
    reinterpret_cast<ushort4*>(out)[i] = o;
  }
}

// ---------------------------------------------------------------- rope tables (2048 x 32)
__global__ void k_rope_table(float* __restrict__ cost, float* __restrict__ sint) {
  const int idx = blockIdx.x * 256 + threadIdx.x;  // 65536
  const int s = idx >> 5, fi = idx & 31;
  const double invf = pow(10000.0, -(double)fi / 32.0);
  const float ang = (float)s * (float)invf;
  cost[idx] = (float)cos((double)ang);
  sint[idx] = (float)sin((double)ang);
}

// ---------------------------------------------------------------- bf16 GEMM  C[M][N] = A[M][K]*B[N][K]^T + bias
__global__ __launch_bounds__(256) void k_gemm_bt(
    const unsigned short* __restrict__ A, const unsigned short* __restrict__ B,
    const float* __restrict__ bias, float* __restrict__ C, int M, int N, int K) {
  __shared__ unsigned short As[128 * 32], Bs[128 * 32];
  const int tid = threadIdx.x, l = tid & 63, w = tid >> 6;
  const int wr = w >> 1, wc = w & 1;
  const int m0 = blockIdx.x * 128, n0 = blockIdx.y * 128;
  const int srow = tid >> 2, scol = (tid & 3) * 8;
  f32x4 acc[4][4] = {};
  for (int k0 = 0; k0 < K; k0 += 32) {
    s16x8 a0 = *(const s16x8*)(A + (size_t)(m0 + srow) * K + k0 + scol);
    s16x8 a1 = *(const s16x8*)(A + (size_t)(m0 + 64 + srow) * K + k0 + scol);
    s16x8 b0 = *(const s16x8*)(B + (size_t)(n0 + srow) * K + k0 + scol);
    s16x8 b1 = *(const s16x8*)(B + (size_t)(n0 + 64 + srow) * K + k0 + scol);
    __syncthreads();
    *(s16x8*)&As[srow * 32 + scol] = a0;
    *(s16x8*)&As[(64 + srow) * 32 + scol] = a1;
    *(s16x8*)&Bs[srow * 32 + scol] = b0;
    *(s16x8*)&Bs[(64 + srow) * 32 + scol] = b1;
    __syncthreads();
    s16x8 af[4], bf[4];
#pragma unroll
    for (int i = 0; i < 4; i++)
      af[i] = *(const s16x8*)&As[(wr * 64 + i * 16 + (l & 15)) * 32 + (l >> 4) * 8];
#pragma unroll
    for (int j = 0; j < 4; j++)
      bf[j] = *(const s16x8*)&Bs[(wc * 64 + j * 16 + (l & 15)) * 32 + (l >> 4) * 8];
#pragma unroll
    for (int i = 0; i < 4; i++)
#pragma unroll
      for (int j = 0; j < 4; j++)
        acc[i][j] = __builtin_amdgcn_mfma_f32_16x16x32_bf16(af[i], bf[j], acc[i][j], 0, 0, 0);
  }
#pragma unroll
  for (int i = 0; i < 4; i++) {
    const int row = m0 + wr * 64 + i * 16 + (l >> 4) * 4;
#pragma unroll
    for (int j = 0; j < 4; j++) {
      const int col = n0 + wc * 64 + j * 16 + (l & 15);
      const float bv = bias ? bias[col] : 0.f;
#pragma unroll
      for (int r = 0; r < 4; r++) C[(size_t)(row + r) * N + col] = acc[i][j][r] + bv;
    }
  }
}

// ---------------------------------------------------------------- RoPE + relayout
// rotate_half pairs heads h^8 (sign - for h<8); tables indexed by (s, d&31).
__global__ void k_rope_relayout(const float* __restrict__ qkv, const float* __restrict__ cost,
                                const float* __restrict__ sint,
                                unsigned short* __restrict__ qh, unsigned short* __restrict__ kh,
                                unsigned short* __restrict__ vt) {
  const int s = blockIdx.x, t = threadIdx.x;
  const float* row = qkv + (size_t)s * 3072;
  const int c = t * 4;
  const int d = c >> 4;
  const int hbase = c & 15;
  const float cv = cost[s * 32 + (d & 31)];
  const float sv = sint[s * 32 + (d & 31)];
  const float sgn = (hbase < 8) ? -1.f : 1.f;
  {
    float4 v = *(const float4*)(row + c);
    float4 v2 = *(const float4*)(row + (c ^ 8));
    const float* vp = (const float*)&v;
    const float* vp2 = (const float*)&v2;
#pragma unroll
    for (int i = 0; i < 4; i++) {
      float val = vp[i] * cv + sgn * vp2[i] * sv;
      qh[(size_t)(hbase + i) * (2048 * 64) + s * 64 + d] = f2bf(val);
    }
  }
  {
    float4 v = *(const float4*)(row + 1024 + c);
    float4 v2 = *(const float4*)(row + 1024 + (c ^ 8));
    const float* vp = (const float*)&v;
    const float* vp2 = (const float*)&v2;
#pragma unroll
    for (int i = 0; i < 4; i++) {
      float val = vp[i] * cv + sgn * vp2[i] * sv;
      kh[(size_t)(hbase + i) * (2048 * 64) + s * 64 + d] = f2bf(val);
    }
  }
  {
    float4 v = *(const float4*)(row + 2048 + c);
    const float* vp = (const float*)&v;
#pragma unroll
    for (int i = 0; i < 4; i++)
      vt[(size_t)(hbase + i) * (64 * 2048) + (size_t)d * 2048 + s] = f2bf(vp[i]);
  }
}

// ---------------------------------------------------------------- attention (round-2 structure, XCD-aware grid)
// grid (x = hg*4+ks = 8 -> one (hg,ks) partition per XCD, z = jt bit-reversed),
// 512 threads (8 waves, 1 head/wave); 32 q-rows, k-range 512 (16 iters of 32).
struct Stage {
  float4 b0, b1, b2, b3;
  int4 m0, m1, m2, m3;
};

DI void stage_load(Stage& st, const float* bp0, const float* bp1,
                   const int* mp0, const int* mp1, int it) {
  const size_t off = (size_t)it * 512;  // 32 k * 16 h floats
  st.b0 = *(const float4*)(bp0 + off);
  st.b1 = *(const float4*)(bp0 + off + 4);
  st.b2 = *(const float4*)(bp1 + off);
  st.b3 = *(const float4*)(bp1 + off + 4);
  st.m0 = *(const int4*)(mp0 + off);
  st.m1 = *(const int4*)(mp0 + off + 4);
  st.m2 = *(const int4*)(mp1 + off);
  st.m3 = *(const int4*)(mp1 + off + 4);
}

DI void stage_write4(unsigned short* dst, const float4& b, const int4& m, int hrbase) {
  const float* bv = (const float*)&b;
  const int* mv = (const int*)&m;
#pragma unroll
  for (int q = 0; q < 4; q++)
    dst[(hrbase + q) * 34] = f2bf(mv[q] ? bv[q] : -1.0e8f);
}

DI void stage_write(const Stage& st, unsigned short* bm, int kr, int jr) {
  unsigned short* d0 = bm + (kr * 8) * 34 + jr;
  stage_write4(d0, st.b0, st.m0, 0);
  stage_write4(d0, st.b1, st.m1, 4);
  unsigned short* d1 = d0 + 16;
  stage_write4(d1, st.b2, st.m2, 0);
  stage_write4(d1, st.b3, st.m3, 4);
}

DI void load_kv(s16x8 (&kf)[4], s16x8 (&vf)[4],
                const unsigned short* kb, const unsigned short* vb, int it) {
  const unsigned short* kp = kb + (size_t)it * (32 * 64);
#pragma unroll
  for (int ds = 0; ds < 4; ds++) kf[ds] = *(const s16x8*)(kp + ds * 16);
  const unsigned short* vp = vb + (size_t)it * 32;
  vf[0] = *(const s16x8*)(vp);                 // s=0 dt=0
  vf[1] = *(const s16x8*)(vp + 32 * 2048);     // s=0 dt=1
  vf[2] = *(const s16x8*)(vp + 16);            // s=1 dt=0
  vf[3] = *(const s16x8*)(vp + 32 * 2048 + 16);// s=1 dt=1
}

DI void attn_step(const s16x8 (&kf)[4], const s16x8 (&vf)[4], const s16x8 (&qf)[4],
                  const unsigned short* bm, int hi, int ln, int w,
                  f32x16& o0, f32x16& o1, float& mrun, float& lrun) {
  // S^T = K * Q^T : reg r holds S^T[kl][j=ln], kl=(r&3)+8*(r>>2)+4*hi
  f32x16 st = {};
#pragma unroll
  for (int ds = 0; ds < 4; ds++)
    st = __builtin_amdgcn_mfma_f32_32x32x16_bf16(kf[ds], qf[ds], st, 0, 0, 0);
  float p[16];
  float tmax = -3.0e38f;
#pragma unroll
  for (int r = 0; r < 16; r++) {
    const int kl = (r & 3) + 8 * (r >> 2) + 4 * hi;
    const float b = bf2f(bm[(kl * 8 + w) * 34 + ln]);
    const float sv = st[r] * 0.125f + b;
    p[r] = sv;
    tmax = fmaxf(tmax, sv);
  }
  tmax = fmaxf(tmax, __shfl_xor(tmax, 32));
  const float mnew = fmaxf(mrun, tmax);
  const float sc = __expf(mrun - mnew);
  float psum = 0.f;
#pragma unroll
  for (int r = 0; r < 16; r++) { p[r] = __expf(p[r] - mnew); psum += p[r]; }
  psum += __shfl_xor(psum, 32);
  lrun = lrun * sc + psum;
  mrun = mnew;
#pragma unroll
  for (int r = 0; r < 16; r++) {
    const int jj = (r & 3) + 8 * (r >> 2) + 4 * hi;
    const float s2 = __shfl(sc, jj);
    o0[r] *= s2;
    o1[r] *= s2;
  }
  unsigned pk[8];
#pragma unroll
  for (int q = 0; q < 8; q++)
    pk[q] = (unsigned)f2bf(p[2 * q]) | ((unsigned)f2bf(p[2 * q + 1]) << 16);
#pragma unroll
  for (int s = 0; s < 2; s++) {
    const unsigned a0 = pk[4 * s + 0], a1 = pk[4 * s + 1];
    const unsigned a2 = pk[4 * s + 2], a3 = pk[4 * s + 3];
    const unsigned x0 = (unsigned)__shfl_xor((int)a0, 32);
    const unsigned x1 = (unsigned)__shfl_xor((int)a1, 32);
    const unsigned x2 = (unsigned)__shfl_xor((int)a2, 32);
    const unsigned x3 = (unsigned)__shfl_xor((int)a3, 32);
    union { int4 i; s16x8 v; } u;
    u.i.x = (int)(hi ? x2 : a0);
    u.i.y = (int)(hi ? x3 : a1);
    u.i.z = (int)(hi ? a2 : x0);
    u.i.w = (int)(hi ? a3 : x1);
    o0 = __builtin_amdgcn_mfma_f32_32x32x16_bf16(u.v, vf[2 * s + 0], o0, 0, 0, 0);
    o1 = __builtin_amdgcn_mfma_f32_32x32x16_bf16(u.v, vf[2 * s + 1], o1, 0, 0, 0);
  }
}

__global__ __launch_bounds__(512) void k_attn(
    const float* __restrict__ bias, const int* __restrict__ mask,
    const unsigned short* __restrict__ qh, const unsigned short* __restrict__ kh,
    const unsigned short* __restrict__ vt,
    float* __restrict__ Opart, float* __restrict__ ML) {
  const int tid = threadIdx.x, l = tid & 63, w = tid >> 6;
  const int hi = l >> 5, ln = l & 31;
  // x = hg*4+ks (8 values -> 1:1 with XCDs); z = jt bit-reversed (spread scan)
  const int hg = blockIdx.x >> 2, ks = blockIdx.x & 3;
  const int z = blockIdx.z;
  const int jt = ((z & 1) << 5) | ((z & 2) << 3) | ((z & 4) << 1) |
                 ((z & 8) >> 1) | ((z & 16) >> 3) | ((z & 32) >> 5);
  const int j0 = jt * 32, h = hg * 8 + w, kstart = ks * 512;
  __shared__ unsigned short bm[32 * 8 * 34];

  s16x8 qf[4];
  {
    const unsigned short* qb = qh + ((size_t)h * 2048 + (j0 + ln)) * 64 + 8 * hi;
#pragma unroll
    for (int ds = 0; ds < 4; ds++) qf[ds] = *(const s16x8*)(qb + ds * 16);
  }

  const int kr = (l & 3) + 4 * w;  // 0..31
  const int jr = (l >> 2) & 15;    // 0..15
  const size_t rowstep = (size_t)2048 * 16;
  const size_t base0 = ((size_t)(j0 + jr) * 2048 + (kstart + kr)) * 16 + hg * 8;
  const float* bp0 = bias + base0;
  const float* bp1 = bp0 + 16 * rowstep;
  const int* mp0 = mask + base0;
  const int* mp1 = mp0 + 16 * rowstep;

  const unsigned short* kb = kh + ((size_t)h * 2048 + (kstart + ln)) * 64 + 8 * hi;
  const unsigned short* vb = vt + (size_t)h * 64 * 2048 + (size_t)ln * 2048 + kstart + 8 * hi;

  f32x16 o0 = {}, o1 = {};
  float mrun = -3.0e38f, lrun = 0.f;

  Stage sA, sB;
  s16x8 kfA[4], vfA[4], kfB[4], vfB[4];
  stage_load(sA, bp0, bp1, mp0, mp1, 0);
  load_kv(kfA, vfA, kb, vb, 0);

  for (int it = 0; it < 16; it += 2) {
    stage_write(sA, bm, kr, jr);
    __syncthreads();
    stage_load(sB, bp0, bp1, mp0, mp1, it + 1);
    load_kv(kfB, vfB, kb, vb, it + 1);
    attn_step(kfA, vfA, qf, bm, hi, ln, w, o0, o1, mrun, lrun);
    __syncthreads();
    stage_write(sB, bm, kr, jr);
    __syncthreads();
    if (it + 2 < 16) {
      stage_load(sA, bp0, bp1, mp0, mp1, it + 2);
      load_kv(kfA, vfA, kb, vb, it + 2);
    }
    attn_step(kfB, vfB, qf, bm, hi, ln, w, o0, o1, mrun, lrun);
    __syncthreads();
  }

  // partial O: [ks][jt][hg][j 32][h 8][d 64] fp32
  float* ob = Opart + ((((size_t)ks * 64 + jt) * 2 + hg) * 32) * 512;
#pragma unroll
  for (int r = 0; r < 16; r++) {
    const int jj = (r & 3) + 8 * (r >> 2) + 4 * hi;
    ob[(size_t)jj * 512 + w * 64 + ln] = o0[r];
    ob[(size_t)jj * 512 + w * 64 + 32 + ln] = o1[r];
  }
  if (hi == 0) {
    float* mlp = ML + (((((size_t)ks * 64 + jt) * 2 + hg) * 32 + ln) * 8 + w) * 2;
    mlp[0] = mrun;
    mlp[1] = lrun;
  }
}

// ---------------------------------------------------------------- combine k-splits -> attn_flat bf16 [2048][1024]
__global__ void k_combine(const float* __restrict__ Opart, const float* __restrict__ ML,
                          unsigned short* __restrict__ attn_flat) {
  const int j = blockIdx.x, t = threadIdx.x;  // 2048 x 256
  const int jt = j >> 5, jl = j & 31;
  const int d = t >> 2;
  const size_t base2 = ((size_t)jt * 2) * 32 + jl;  // + hg*32 added per element
  unsigned short tmp[4];
#pragma unroll
  for (int q = 0; q < 4; q++) {
    const int hh = 4 * (t & 3) + q;
    const int hg = hh >> 3, hl = hh & 7;
    const size_t slotb = base2 + (size_t)hg * 32;
    float m[4], lv[4];
#pragma unroll
    for (int ksi = 0; ksi < 4; ksi++) {
      const float* mlp = ML + (((size_t)ksi * 4096 + slotb) * 8 + hl) * 2;
      m[ksi] = mlp[0];
      lv[ksi] = mlp[1];
    }
    const float M = fmaxf(fmaxf(m[0], m[1]), fmaxf(m[2], m[3]));
    float L = 0.f, acc = 0.f;
#pragma unroll
    for (int ksi = 0; ksi < 4; ksi++) {
      const float e = __expf(m[ksi] - M);
      L += lv[ksi] * e;
      acc += Opart[((size_t)ksi * 4096 + slotb) * 512 + hl * 64 + d] * e;
    }
    tmp[q] = f2bf(acc / L);
  }
  ushort4 outv;
  outv.x = tmp[0]; outv.y = tmp[1]; outv.z = tmp[2]; outv.w = tmp[3];
  *(ushort4*)(attn_flat + (size_t)j * 1024 + t * 4) = outv;
}

// ---------------------------------------------------------------- launch
extern "C" void kernel_launch(void* const* d_in, const int* in_sizes, int n_in,
                              void* d_out, int out_size, void* d_ws, size_t ws_size,
                              hipStream_t stream) {
  const float* x     = (const float*)d_in[0];
  const float* bias  = (const float*)d_in[1];
  const int*   mask  = (const int*)d_in[2];
  const float* w_qkv = (const float*)d_in[3];
  const float* b_qkv = (const float*)d_in[4];
  const float* w_out = (const float*)d_in[5];
  const float* b_out = (const float*)d_in[6];
  float* out = (float*)d_out;

  char* ws = (char*)d_ws;
  unsigned short* xb   = (unsigned short*)(ws);
  unsigned short* wqb  = (unsigned short*)(ws + ((size_t)4 << 20));
  unsigned short* wob  = (unsigned short*)(ws + ((size_t)10 << 20));
  float* cost          = (float*)(ws + ((size_t)12 << 20));
  float* sint          = (float*)(ws + ((size_t)12 << 20) + (256 << 10));
  float* qkv           = (float*)(ws + ((size_t)13 << 20));
  unsigned short* qhp  = (unsigned short*)(ws + ((size_t)37 << 20));
  unsigned short* khp  = (unsigned short*)(ws + ((size_t)41 << 20));
  unsigned short* vtp  = (unsigned short*)(ws + ((size_t)45 << 20));
  unsigned short* af   = (unsigned short*)(ws + ((size_t)49 << 20));
  float* Opart         = (float*)(ws + ((size_t)53 << 20));
  float* ML            = (float*)(ws + ((size_t)85 << 20));

  k_cvt_bf16<<<dim3(512), dim3(256), 0, stream>>>(x, xb, 2048 * 1024 / 4);
  k_cvt_bf16<<<dim3(512), dim3(256), 0, stream>>>(w_qkv, wqb, 3072 * 1024 / 4);
  k_cvt_bf16<<<dim3(512), dim3(256), 0, stream>>>(w_out, wob, 1024 * 1024 / 4);
  k_rope_table<<<dim3(256), dim3(256), 0, stream>>>(cost, sint);
  k_gemm_bt<<<dim3(16, 24), dim3(256), 0, stream>>>(xb, wqb, b_qkv, qkv, 2048, 3072, 1024);
  k_rope_relayout<<<dim3(2048), dim3(256), 0, stream>>>(qkv, cost, sint, qhp, khp, vtp);
  k_attn<<<dim3(8, 1, 64), dim3(512), 0, stream>>>(bias, mask, qhp, khp, vtp, Opart, ML);
  k_combine<<<dim3(2048), dim3(256), 0, stream>>>(Opart, ML, af);
  k_gemm_bt<<<dim3(16, 8), dim3(256), 0, stream>>>(af, wob, b_out, out, 2048, 1024, 1024);
}

// Round 11
// 320.769 us; speedup vs baseline: 1.2494x; 1.0041x over previous
//
#include <hip/hip_runtime.h>
#include <stdint.h>
#include <math.h>

using f32x4  = __attribute__((ext_vector_type(4)))  float;
using f32x16 = __attribute__((ext_vector_type(16))) float;
using s16x8  = __attribute__((ext_vector_type(8)))  short;

#define DI __device__ __forceinline__

DI unsigned short f2bf(float f) {
  unsigned u = __float_as_uint(f);
  u += 0x7FFFu + ((u >> 16) & 1u);
  return (unsigned short)(u >> 16);
}
DI float bf2f(unsigned short h) { return __uint_as_float((unsigned)h << 16); }

// ---------------------------------------------------------------- f32 -> bf16
__global__ void k_cvt_bf16(const float* __restrict__ in, unsigned short* __restrict__ out, int n4) {
  int i = blockIdx.x * blockDim.x + threadIdx.x;
  const int stride = gridDim.x * blockDim.x;
  for (; i < n4; i += stride) {
    float4 v = reinterpret_cast<const float4*>(in)[i];
    ushort4 o;
    o.x = f2bf(v.x); o.y = f2bf(v.y); o.z = f2bf(v.z); o.w = f2bf(v.w);
    reinterpret_cast<ushort4*>(out)[i] = o;
  }
}

// ---------------------------------------------------------------- rope tables (2048 x 32)
__global__ void k_rope_table(float* __restrict__ cost, float* __restrict__ sint) {
  const int idx = blockIdx.x * 256 + threadIdx.x;  // 65536
  const int s = idx >> 5, fi = idx & 31;
  const double invf = pow(10000.0, -(double)fi / 32.0);
  const float ang = (float)s * (float)invf;
  cost[idx] = (float)cos((double)ang);
  sint[idx] = (float)sin((double)ang);
}

// ---------------------------------------------------------------- bf16 GEMM  C = A*B^T + bias
// writes fp32 (C) or bf16 (C16) depending on which pointer is non-null
__global__ __launch_bounds__(256) void k_gemm_bt(
    const unsigned short* __restrict__ A, const unsigned short* __restrict__ B,
    const float* __restrict__ bias, float* __restrict__ C,
    unsigned short* __restrict__ C16, int M, int N, int K) {
  __shared__ unsigned short As[128 * 32], Bs[128 * 32];
  const int tid = threadIdx.x, l = tid & 63, w = tid >> 6;
  const int wr = w >> 1, wc = w & 1;
  const int m0 = blockIdx.x * 128, n0 = blockIdx.y * 128;
  const int srow = tid >> 2, scol = (tid & 3) * 8;
  f32x4 acc[4][4] = {};
  for (int k0 = 0; k0 < K; k0 += 32) {
    s16x8 a0 = *(const s16x8*)(A + (size_t)(m0 + srow) * K + k0 + scol);
    s16x8 a1 = *(const s16x8*)(A + (size_t)(m0 + 64 + srow) * K + k0 + scol);
    s16x8 b0 = *(const s16x8*)(B + (size_t)(n0 + srow) * K + k0 + scol);
    s16x8 b1 = *(const s16x8*)(B + (size_t)(n0 + 64 + srow) * K + k0 + scol);
    __syncthreads();
    *(s16x8*)&As[srow * 32 + scol] = a0;
    *(s16x8*)&As[(64 + srow) * 32 + scol] = a1;
    *(s16x8*)&Bs[srow * 32 + scol] = b0;
    *(s16x8*)&Bs[(64 + srow) * 32 + scol] = b1;
    __syncthreads();
    s16x8 af[4], bf[4];
#pragma unroll
    for (int i = 0; i < 4; i++)
      af[i] = *(const s16x8*)&As[(wr * 64 + i * 16 + (l & 15)) * 32 + (l >> 4) * 8];
#pragma unroll
    for (int j = 0; j < 4; j++)
      bf[j] = *(const s16x8*)&Bs[(wc * 64 + j * 16 + (l & 15)) * 32 + (l >> 4) * 8];
#pragma unroll
    for (int i = 0; i < 4; i++)
#pragma unroll
      for (int j = 0; j < 4; j++)
        acc[i][j] = __builtin_amdgcn_mfma_f32_16x16x32_bf16(af[i], bf[j], acc[i][j], 0, 0, 0);
  }
#pragma unroll
  for (int i = 0; i < 4; i++) {
    const int row = m0 + wr * 64 + i * 16 + (l >> 4) * 4;
#pragma unroll
    for (int j = 0; j < 4; j++) {
      const int col = n0 + wc * 64 + j * 16 + (l & 15);
      const float bv = bias ? bias[col] : 0.f;
      if (C16) {
#pragma unroll
        for (int r = 0; r < 4; r++) C16[(size_t)(row + r) * N + col] = f2bf(acc[i][j][r] + bv);
      } else {
#pragma unroll
        for (int r = 0; r < 4; r++) C[(size_t)(row + r) * N + col] = acc[i][j][r] + bv;
      }
    }
  }
}

// ---------------------------------------------------------------- RoPE + relayout (bf16 qkv input)
// rotate_half pairs heads h^8 (sign - for h<8); tables indexed by (s, d&31).
__global__ void k_rope_relayout(const unsigned short* __restrict__ qkv, const float* __restrict__ cost,
                                const float* __restrict__ sint,
                                unsigned short* __restrict__ qh, unsigned short* __restrict__ kh,
                                unsigned short* __restrict__ vt) {
  const int s = blockIdx.x, t = threadIdx.x;
  const unsigned short* row = qkv + (size_t)s * 3072;
  const int c = t * 4;
  const int d = c >> 4;
  const int hbase = c & 15;
  const float cv = cost[s * 32 + (d & 31)];
  const float sv = sint[s * 32 + (d & 31)];
  const float sgn = (hbase < 8) ? -1.f : 1.f;
  {
    ushort4 v = *(const ushort4*)(row + c);
    ushort4 v2 = *(const ushort4*)(row + (c ^ 8));
    const unsigned short* vp = (const unsigned short*)&v;
    const unsigned short* vp2 = (const unsigned short*)&v2;
#pragma unroll
    for (int i = 0; i < 4; i++) {
      float val = bf2f(vp[i]) * cv + sgn * bf2f(vp2[i]) * sv;
      qh[(size_t)(hbase + i) * (2048 * 64) + s * 64 + d] = f2bf(val);
    }
  }
  {
    ushort4 v = *(const ushort4*)(row + 1024 + c);
    ushort4 v2 = *(const ushort4*)(row + 1024 + (c ^ 8));
    const unsigned short* vp = (const unsigned short*)&v;
    const unsigned short* vp2 = (const unsigned short*)&v2;
#pragma unroll
    for (int i = 0; i < 4; i++) {
      float val = bf2f(vp[i]) * cv + sgn * bf2f(vp2[i]) * sv;
      kh[(size_t)(hbase + i) * (2048 * 64) + s * 64 + d] = f2bf(val);
    }
  }
  {
    ushort4 v = *(const ushort4*)(row + 2048 + c);
    const unsigned short* vp = (const unsigned short*)&v;
#pragma unroll
    for (int i = 0; i < 4; i++)
      vt[(size_t)(hbase + i) * (64 * 2048) + (size_t)d * 2048 + s] = vp[i];
  }
}

// ---------------------------------------------------------------- attention (round-2 structure, XCD-aware grid)
struct Stage {
  float4 b0, b1, b2, b3;
  int4 m0, m1, m2, m3;
};

DI void stage_load(Stage& st, const float* bp0, const float* bp1,
                   const int* mp0, const int* mp1, int it) {
  const size_t off = (size_t)it * 512;  // 32 k * 16 h floats
  st.b0 = *(const float4*)(bp0 + off);
  st.b1 = *(const float4*)(bp0 + off + 4);
  st.b2 = *(const float4*)(bp1 + off);
  st.b3 = *(const float4*)(bp1 + off + 4);
  st.m0 = *(const int4*)(mp0 + off);
  st.m1 = *(const int4*)(mp0 + off + 4);
  st.m2 = *(const int4*)(mp1 + off);
  st.m3 = *(const int4*)(mp1 + off + 4);
}

DI void stage_write4(unsigned short* dst, const float4& b, const int4& m, int hrbase) {
  const float* bv = (const float*)&b;
  const int* mv = (const int*)&m;
#pragma unroll
  for (int q = 0; q < 4; q++)
    dst[(hrbase + q) * 34] = f2bf(mv[q] ? bv[q] : -1.0e8f);
}

DI void stage_write(const Stage& st, unsigned short* bm, int kr, int jr) {
  unsigned short* d0 = bm + (kr * 8) * 34 + jr;
  stage_write4(d0, st.b0, st.m0, 0);
  stage_write4(d0, st.b1, st.m1, 4);
  unsigned short* d1 = d0 + 16;
  stage_write4(d1, st.b2, st.m2, 0);
  stage_write4(d1, st.b3, st.m3, 4);
}

DI void load_kv(s16x8 (&kf)[4], s16x8 (&vf)[4],
                const unsigned short* kb, const unsigned short* vb, int it) {
  const unsigned short* kp = kb + (size_t)it * (32 * 64);
#pragma unroll
  for (int ds = 0; ds < 4; ds++) kf[ds] = *(const s16x8*)(kp + ds * 16);
  const unsigned short* vp = vb + (size_t)it * 32;
  vf[0] = *(const s16x8*)(vp);
  vf[1] = *(const s16x8*)(vp + 32 * 2048);
  vf[2] = *(const s16x8*)(vp + 16);
  vf[3] = *(const s16x8*)(vp + 32 * 2048 + 16);
}

DI void attn_step(const s16x8 (&kf)[4], const s16x8 (&vf)[4], const s16x8 (&qf)[4],
                  const unsigned short* bm, int hi, int ln, int w,
                  f32x16& o0, f32x16& o1, float& mrun, float& lrun) {
  f32x16 st = {};
#pragma unroll
  for (int ds = 0; ds < 4; ds++)
    st = __builtin_amdgcn_mfma_f32_32x32x16_bf16(kf[ds], qf[ds], st, 0, 0, 0);
  float p[16];
  float tmax = -3.0e38f;
#pragma unroll
  for (int r = 0; r < 16; r++) {
    const int kl = (r & 3) + 8 * (r >> 2) + 4 * hi;
    const float b = bf2f(bm[(kl * 8 + w) * 34 + ln]);
    const float sv = st[r] * 0.125f + b;
    p[r] = sv;
    tmax = fmaxf(tmax, sv);
  }
  tmax = fmaxf(tmax, __shfl_xor(tmax, 32));
  const float mnew = fmaxf(mrun, tmax);
  const float sc = __expf(mrun - mnew);
  float psum = 0.f;
#pragma unroll
  for (int r = 0; r < 16; r++) { p[r] = __expf(p[r] - mnew); psum += p[r]; }
  psum += __shfl_xor(psum, 32);
  lrun = lrun * sc + psum;
  mrun = mnew;
#pragma unroll
  for (int r = 0; r < 16; r++) {
    const int jj = (r & 3) + 8 * (r >> 2) + 4 * hi;
    const float s2 = __shfl(sc, jj);
    o0[r] *= s2;
    o1[r] *= s2;
  }
  unsigned pk[8];
#pragma unroll
  for (int q = 0; q < 8; q++)
    pk[q] = (unsigned)f2bf(p[2 * q]) | ((unsigned)f2bf(p[2 * q + 1]) << 16);
#pragma unroll
  for (int s = 0; s < 2; s++) {
    const unsigned a0 = pk[4 * s + 0], a1 = pk[4 * s + 1];
    const unsigned a2 = pk[4 * s + 2], a3 = pk[4 * s + 3];
    const unsigned x0 = (unsigned)__shfl_xor((int)a0, 32);
    const unsigned x1 = (unsigned)__shfl_xor((int)a1, 32);
    const unsigned x2 = (unsigned)__shfl_xor((int)a2, 32);
    const unsigned x3 = (unsigned)__shfl_xor((int)a3, 32);
    union { int4 i; s16x8 v; } u;
    u.i.x = (int)(hi ? x2 : a0);
    u.i.y = (int)(hi ? x3 : a1);
    u.i.z = (int)(hi ? a2 : x0);
    u.i.w = (int)(hi ? a3 : x1);
    o0 = __builtin_amdgcn_mfma_f32_32x32x16_bf16(u.v, vf[2 * s + 0], o0, 0, 0, 0);
    o1 = __builtin_amdgcn_mfma_f32_32x32x16_bf16(u.v, vf[2 * s + 1], o1, 0, 0, 0);
  }
}

__global__ __launch_bounds__(512) void k_attn(
    const float* __restrict__ bias, const int* __restrict__ mask,
    const unsigned short* __restrict__ qh, const unsigned short* __restrict__ kh,
    const unsigned short* __restrict__ vt,
    unsigned short* __restrict__ Opart, float* __restrict__ ML) {
  const int tid = threadIdx.x, l = tid & 63, w = tid >> 6;
  const int hi = l >> 5, ln = l & 31;
  const int hg = blockIdx.x >> 2, ks = blockIdx.x & 3;
  const int z = blockIdx.z;
  const int jt = ((z & 1) << 5) | ((z & 2) << 3) | ((z & 4) << 1) |
                 ((z & 8) >> 1) | ((z & 16) >> 3) | ((z & 32) >> 5);
  const int j0 = jt * 32, h = hg * 8 + w, kstart = ks * 512;
  __shared__ unsigned short bm[32 * 8 * 34];

  s16x8 qf[4];
  {
    const unsigned short* qb = qh + ((size_t)h * 2048 + (j0 + ln)) * 64 + 8 * hi;
#pragma unroll
    for (int ds = 0; ds < 4; ds++) qf[ds] = *(const s16x8*)(qb + ds * 16);
  }

  const int kr = (l & 3) + 4 * w;
  const int jr = (l >> 2) & 15;
  const size_t rowstep = (size_t)2048 * 16;
  const size_t base0 = ((size_t)(j0 + jr) * 2048 + (kstart + kr)) * 16 + hg * 8;
  const float* bp0 = bias + base0;
  const float* bp1 = bp0 + 16 * rowstep;
  const int* mp0 = mask + base0;
  const int* mp1 = mp0 + 16 * rowstep;

  const unsigned short* kb = kh + ((size_t)h * 2048 + (kstart + ln)) * 64 + 8 * hi;
  const unsigned short* vb = vt + (size_t)h * 64 * 2048 + (size_t)ln * 2048 + kstart + 8 * hi;

  f32x16 o0 = {}, o1 = {};
  float mrun = -3.0e38f, lrun = 0.f;

  Stage sA, sB;
  s16x8 kfA[4], vfA[4], kfB[4], vfB[4];
  stage_load(sA, bp0, bp1, mp0, mp1, 0);
  load_kv(kfA, vfA, kb, vb, 0);

  for (int it = 0; it < 16; it += 2) {
    stage_write(sA, bm, kr, jr);
    __syncthreads();
    stage_load(sB, bp0, bp1, mp0, mp1, it + 1);
    load_kv(kfB, vfB, kb, vb, it + 1);
    attn_step(kfA, vfA, qf, bm, hi, ln, w, o0, o1, mrun, lrun);
    __syncthreads();
    stage_write(sB, bm, kr, jr);
    __syncthreads();
    if (it + 2 < 16) {
      stage_load(sA, bp0, bp1, mp0, mp1, it + 2);
      load_kv(kfA, vfA, kb, vb, it + 2);
    }
    attn_step(kfB, vfB, qf, bm, hi, ln, w, o0, o1, mrun, lrun);
    __syncthreads();
  }

  // partial O (bf16): [ks][jt][hg][j 32][h 8][d 64]
  unsigned short* ob = Opart + ((((size_t)ks * 64 + jt) * 2 + hg) * 32) * 512;
#pragma unroll
  for (int r = 0; r < 16; r++) {
    const int jj = (r & 3) + 8 * (r >> 2) + 4 * hi;
    ob[(size_t)jj * 512 + w * 64 + ln] = f2bf(o0[r]);
    ob[(size_t)jj * 512 + w * 64 + 32 + ln] = f2bf(o1[r]);
  }
  if (hi == 0) {
    float* mlp = ML + (((((size_t)ks * 64 + jt) * 2 + hg) * 32 + ln) * 8 + w) * 2;
    mlp[0] = mrun;
    mlp[1] = lrun;
  }
}

// ---------------------------------------------------------------- combine k-splits -> attn_flat bf16 [2048][1024]
__global__ void k_combine(const unsigned short* __restrict__ Opart, const float* __restrict__ ML,
                          unsigned short* __restrict__ attn_flat) {
  const int j = blockIdx.x, t = threadIdx.x;  // 2048 x 256
  const int jt = j >> 5, jl = j & 31;
  const int d = t >> 2;
  const size_t base2 = ((size_t)jt * 2) * 32 + jl;
  unsigned short tmp[4];
#pragma unroll
  for (int q = 0; q < 4; q++) {
    const int hh = 4 * (t & 3) + q;
    const int hg = hh >> 3, hl = hh & 7;
    const size_t slotb = base2 + (size_t)hg * 32;
    float m[4], lv[4];
#pragma unroll
    for (int ksi = 0; ksi < 4; ksi++) {
      const float* mlp = ML + (((size_t)ksi * 4096 + slotb) * 8 + hl) * 2;
      m[ksi] = mlp[0];
      lv[ksi] = mlp[1];
    }
    const float M = fmaxf(fmaxf(m[0], m[1]), fmaxf(m[2], m[3]));
    float L = 0.f, acc = 0.f;
#pragma unroll
    for (int ksi = 0; ksi < 4; ksi++) {
      const float e = __expf(m[ksi] - M);
      L += lv[ksi] * e;
      acc += bf2f(Opart[((size_t)ksi * 4096 + slotb) * 512 + hl * 64 + d]) * e;
    }
    tmp[q] = f2bf(acc / L);
  }
  ushort4 outv;
  outv.x = tmp[0]; outv.y = tmp[1]; outv.z = tmp[2]; outv.w = tmp[3];
  *(ushort4*)(attn_flat + (size_t)j * 1024 + t * 4) = outv;
}

// ---------------------------------------------------------------- launch
extern "C" void kernel_launch(void* const* d_in, const int* in_sizes, int n_in,
                              void* d_out, int out_size, void* d_ws, size_t ws_size,
                              hipStream_t stream) {
  const float* x     = (const float*)d_in[0];
  const float* bias  = (const float*)d_in[1];
  const int*   mask  = (const int*)d_in[2];
  const float* w_qkv = (const float*)d_in[3];
  const float* b_qkv = (const float*)d_in[4];
  const float* w_out = (const float*)d_in[5];
  const float* b_out = (const float*)d_in[6];
  float* out = (float*)d_out;

  char* ws = (char*)d_ws;
  unsigned short* xb    = (unsigned short*)(ws);                      // 4 MB
  unsigned short* wqb   = (unsigned short*)(ws + ((size_t)4 << 20));  // 6 MB
  unsigned short* wob   = (unsigned short*)(ws + ((size_t)10 << 20)); // 2 MB
  float* cost           = (float*)(ws + ((size_t)12 << 20));
  float* sint           = (float*)(ws + ((size_t)12 << 20) + (256 << 10));
  unsigned short* qkv16 = (unsigned short*)(ws + ((size_t)13 << 20)); // 12 MB
  unsigned short* qhp   = (unsigned short*)(ws + ((size_t)37 << 20)); // 4 MB
  unsigned short* khp   = (unsigned short*)(ws + ((size_t)41 << 20)); // 4 MB
  unsigned short* vtp   = (unsigned short*)(ws + ((size_t)45 << 20)); // 4 MB
  unsigned short* af    = (unsigned short*)(ws + ((size_t)49 << 20)); // 4 MB
  unsigned short* Opart = (unsigned short*)(ws + ((size_t)53 << 20)); // 16.8 MB
  float* ML             = (float*)(ws + ((size_t)85 << 20));          // 1 MB

  k_cvt_bf16<<<dim3(512), dim3(256), 0, stream>>>(x, xb, 2048 * 1024 / 4);
  k_cvt_bf16<<<dim3(512), dim3(256), 0, stream>>>(w_qkv, wqb, 3072 * 1024 / 4);
  k_cvt_bf16<<<dim3(512), dim3(256), 0, stream>>>(w_out, wob, 1024 * 1024 / 4);
  k_rope_table<<<dim3(256), dim3(256), 0, stream>>>(cost, sint);
  k_gemm_bt<<<dim3(16, 24), dim3(256), 0, stream>>>(xb, wqb, b_qkv, nullptr, qkv16, 2048, 3072, 1024);
  k_rope_relayout<<<dim3(2048), dim3(256), 0, stream>>>(qkv16, cost, sint, qhp, khp, vtp);
  k_attn<<<dim3(8, 1, 64), dim3(512), 0, stream>>>(bias, mask, qhp, khp, vtp, Opart, ML);
  k_combine<<<dim3(2048), dim3(256), 0, stream>>>(Opart, ML, af);
  k_gemm_bt<<<dim3(16, 8), dim3(256), 0, stream>>>(af, wob, b_out, out, nullptr, 2048, 1024, 1024);
}